// Round 3
// baseline (754.130 us; speedup 1.0000x reference)
//
#include <hip/hip_runtime.h>
#include <hip/hip_bf16.h>
#include <stdint.h>

#define N_V   16384
#define M_E   8192
#define CIN   128
#define COUT  64
#define RCAP  128   // per-vertex edge-list capacity (Poisson(41): overflow ~1e-13)
#define CCAP  192   // per-edge vertex-list capacity (Poisson(82): overflow ~1e-18)
#define CHUNKS 64   // row chunks for atomic-free column transpose
#define RPC   (N_V / CHUNKS)   // 256 rows per chunk

// workspace layout (bytes), all offsets 16B-aligned
#define OFF_ROWCNT  0
#define OFF_COLCNT  (N_V * 4)                         // 65536
#define OFF_ROWLIST (OFF_COLCNT + M_E * 4)            // 98304
#define OFF_COLLIST (OFF_ROWLIST + N_V * RCAP * 2)    // + 4 MB
#define OFF_YV      (OFF_COLLIST + M_E * CCAP * 2)    // + 3 MB
#define OFF_E       (OFF_YV + N_V * COUT * 4)         // + 4 MB
#define OFF_HIST    (OFF_E + M_E * COUT * 4)          // + 2 MB
// total: OFF_HIST + CHUNKS*M_E*4  ~= 15.2 MB

// ---------------------------------------------------------------------------
// K1: stream H once, one wave per row. ZERO atomics: slot assignment via
// wave ballots + popcount prefix; row_cnt is a plain store at the end.
// 32 iterations x 1KB coalesced loads per wave, no dependent vmem in loop.
// ---------------------------------------------------------------------------
__global__ __launch_bounds__(256) void k_rows(
    const uint4* __restrict__ H4,
    int* __restrict__ row_cnt, unsigned short* __restrict__ row_list) {
  int wid  = threadIdx.x >> 6;
  int lane = threadIdx.x & 63;
  int n    = blockIdx.x * 4 + wid;                 // gridDim.x = N_V/4
  const uint4* rp = H4 + (size_t)n * (M_E / 4) + lane;
  unsigned short* rl = row_list + n * RCAP;
  unsigned long long lt = (1ull << lane) - 1ull;   // lane 63: (1<<63)-1, ok
  int off = 0;
#pragma unroll 8
  for (int it = 0; it < (M_E / 4) / 64; ++it) {    // 32 iterations
    uint4 v = rp[it * 64];
    // H entries are 0.0f / 1.0f: nonzero bits <=> nonzero float
    unsigned long long b0 = __ballot(v.x != 0u);
    unsigned long long b1 = __ballot(v.y != 0u);
    unsigned long long b2 = __ballot(v.z != 0u);
    unsigned long long b3 = __ballot(v.w != 0u);
    int t0 = __popcll(b0), t1 = __popcll(b1), t2 = __popcll(b2), t3 = __popcll(b3);
    int total = t0 + t1 + t2 + t3;
    if (total) {                                   // wave-uniform branch
      int mb = (it * 64 + lane) * 4;               // column base for this lane
      if (v.x != 0u) { int p = off + __popcll(b0 & lt);
                       if (p < RCAP) rl[p] = (unsigned short)(mb + 0); }
      if (v.y != 0u) { int p = off + t0 + __popcll(b1 & lt);
                       if (p < RCAP) rl[p] = (unsigned short)(mb + 1); }
      if (v.z != 0u) { int p = off + t0 + t1 + __popcll(b2 & lt);
                       if (p < RCAP) rl[p] = (unsigned short)(mb + 2); }
      if (v.w != 0u) { int p = off + t0 + t1 + t2 + __popcll(b3 & lt);
                       if (p < RCAP) rl[p] = (unsigned short)(mb + 3); }
      off += total;
    }
  }
  if (lane == 0) row_cnt[n] = off < RCAP ? off : RCAP;
}

// ---------------------------------------------------------------------------
// K1b-P1: per-chunk edge histogram via LDS atomics (no global atomics).
// One block per chunk of 256 rows.
// ---------------------------------------------------------------------------
__global__ __launch_bounds__(256) void k_hist(
    const int* __restrict__ row_cnt, const unsigned short* __restrict__ row_list,
    unsigned int* __restrict__ hist) {
  __shared__ unsigned int h[M_E];                  // 32 KB
  for (int i = threadIdx.x; i < M_E; i += 256) h[i] = 0u;
  __syncthreads();
  int n = blockIdx.x * RPC + threadIdx.x;          // gridDim.x = CHUNKS
  int cnt = row_cnt[n];
  const unsigned short* lst = row_list + n * RCAP;
  for (int i = 0; i < cnt; ++i) atomicAdd(&h[lst[i]], 1u);
  __syncthreads();
  unsigned int* out = hist + (size_t)blockIdx.x * M_E;
  for (int i = threadIdx.x; i < M_E; i += 256) out[i] = h[i];
}

// ---------------------------------------------------------------------------
// K1b-P2: exclusive scan over chunks per edge -> per-(chunk,edge) base
// offsets (in place) + total col_cnt. Coalesced, loads prefetchable.
// ---------------------------------------------------------------------------
__global__ __launch_bounds__(256) void k_scan(
    unsigned int* __restrict__ hist, int* __restrict__ col_cnt) {
  int e = blockIdx.x * 256 + threadIdx.x;          // gridDim.x = M_E/256
  unsigned int run = 0;
#pragma unroll 8
  for (int c = 0; c < CHUNKS; ++c) {
    unsigned int hv = hist[(size_t)c * M_E + e];
    hist[(size_t)c * M_E + e] = run;
    run += hv;
  }
  col_cnt[e] = (int)run;
}

// ---------------------------------------------------------------------------
// K1b-P3: re-walk row lists; LDS counters initialized to chunk bases, so
// atomicAdd return IS the global slot. Still zero global atomics.
// ---------------------------------------------------------------------------
__global__ __launch_bounds__(256) void k_fill(
    const int* __restrict__ row_cnt, const unsigned short* __restrict__ row_list,
    const unsigned int* __restrict__ hist, unsigned short* __restrict__ col_list) {
  __shared__ unsigned int h[M_E];                  // 32 KB
  const unsigned int* base = hist + (size_t)blockIdx.x * M_E;
  for (int i = threadIdx.x; i < M_E; i += 256) h[i] = base[i];
  __syncthreads();
  int n = blockIdx.x * RPC + threadIdx.x;
  int cnt = row_cnt[n];
  const unsigned short* lst = row_list + n * RCAP;
  for (int i = 0; i < cnt; ++i) {
    int e = lst[i];
    unsigned int slot = atomicAdd(&h[e], 1u);
    if (slot < CCAP) col_list[e * CCAP + slot] = (unsigned short)n;
  }
}

// ---------------------------------------------------------------------------
// K2: Yv[n,c] = dv[n] * (X[n,:] . W[c,:] + b[c])
// ---------------------------------------------------------------------------
__global__ __launch_bounds__(256) void k_project(
    const float* __restrict__ X, const float* __restrict__ W,
    const float* __restrict__ b, const int* __restrict__ row_cnt,
    float* __restrict__ Yv) {
  int wid  = threadIdx.x >> 6;
  int lane = threadIdx.x & 63;
  int cb   = __builtin_amdgcn_readfirstlane(wid);   // c-block 0..3, forced SGPR
  int n    = blockIdx.x * 64 + lane;                // gridDim.x = 256
  const float* xrow  = X + n * CIN;
  const float* wbase = W + cb * 16 * CIN;

  float acc[16];
#pragma unroll
  for (int j = 0; j < 16; ++j) acc[j] = 0.f;

  for (int k4 = 0; k4 < CIN / 4; ++k4) {
    float4 x = *(const float4*)(xrow + k4 * 4);
#pragma unroll
    for (int j = 0; j < 16; ++j) {
      float4 w = *(const float4*)(wbase + j * CIN + k4 * 4);
      acc[j] += x.x * w.x + x.y * w.y + x.z * w.z + x.w * w.w;
    }
  }

  int cnt  = row_cnt[n];
  float dv = cnt > 0 ? rsqrtf((float)cnt) : 0.f;
  float* yrow = Yv + n * COUT + cb * 16;
#pragma unroll
  for (int g = 0; g < 4; ++g) {
    float4 o;
    o.x = dv * (acc[4 * g + 0] + b[cb * 16 + 4 * g + 0]);
    o.y = dv * (acc[4 * g + 1] + b[cb * 16 + 4 * g + 1]);
    o.z = dv * (acc[4 * g + 2] + b[cb * 16 + 4 * g + 2]);
    o.w = dv * (acc[4 * g + 3] + b[cb * 16 + 4 * g + 3]);
    *(float4*)(yrow + 4 * g) = o;
  }
}

// ---------------------------------------------------------------------------
// K3: E[m,:] = (1/de_cnt[m]) * sum_{n in col_list[m]} Yv[n,:]
// One wave per hyperedge, lane = channel; 8 gathers in flight.
// ---------------------------------------------------------------------------
__global__ __launch_bounds__(256) void k_edge(
    const float* __restrict__ Yv, const int* __restrict__ col_cnt,
    const unsigned short* __restrict__ col_list, float* __restrict__ E) {
  int wid  = threadIdx.x >> 6;
  int lane = threadIdx.x & 63;
  int m    = blockIdx.x * 4 + wid;      // gridDim.x = M_E/4
  int realcnt = col_cnt[m];
  int cnt  = realcnt > CCAP ? CCAP : realcnt;
  const unsigned short* lst = col_list + m * CCAP;
  float acc = 0.f;
  int i = 0;
  for (; i + 8 <= cnt; i += 8) {
    uint4 u = *(const uint4*)(lst + i);
    int n0 = u.x & 0xffff, n1 = u.x >> 16;
    int n2 = u.y & 0xffff, n3 = u.y >> 16;
    int n4 = u.z & 0xffff, n5 = u.z >> 16;
    int n6 = u.w & 0xffff, n7 = u.w >> 16;
    float a0 = Yv[n0 * COUT + lane];
    float a1 = Yv[n1 * COUT + lane];
    float a2 = Yv[n2 * COUT + lane];
    float a3 = Yv[n3 * COUT + lane];
    float a4 = Yv[n4 * COUT + lane];
    float a5 = Yv[n5 * COUT + lane];
    float a6 = Yv[n6 * COUT + lane];
    float a7 = Yv[n7 * COUT + lane];
    acc += ((a0 + a1) + (a2 + a3)) + ((a4 + a5) + (a6 + a7));
  }
  for (; i < cnt; ++i) acc += Yv[(int)lst[i] * COUT + lane];
  float den = realcnt > 0 ? 1.f / (float)realcnt : 0.f;
  E[m * COUT + lane] = den * acc;
}

// ---------------------------------------------------------------------------
// K4: out[n,:] = relu(dv[n] * sum_{m in row_list[n]} E[m,:])
// ---------------------------------------------------------------------------
__global__ __launch_bounds__(256) void k_vertex(
    const float* __restrict__ E, const int* __restrict__ row_cnt,
    const unsigned short* __restrict__ row_list, float* __restrict__ out) {
  int wid  = threadIdx.x >> 6;
  int lane = threadIdx.x & 63;
  int n    = blockIdx.x * 4 + wid;      // gridDim.x = N_V/4
  int cnt  = row_cnt[n];
  const unsigned short* lst = row_list + n * RCAP;
  float acc = 0.f;
  int i = 0;
  for (; i + 8 <= cnt; i += 8) {
    uint4 u = *(const uint4*)(lst + i);
    int m0 = u.x & 0xffff, m1 = u.x >> 16;
    int m2 = u.y & 0xffff, m3 = u.y >> 16;
    int m4 = u.z & 0xffff, m5 = u.z >> 16;
    int m6 = u.w & 0xffff, m7 = u.w >> 16;
    float a0 = E[m0 * COUT + lane];
    float a1 = E[m1 * COUT + lane];
    float a2 = E[m2 * COUT + lane];
    float a3 = E[m3 * COUT + lane];
    float a4 = E[m4 * COUT + lane];
    float a5 = E[m5 * COUT + lane];
    float a6 = E[m6 * COUT + lane];
    float a7 = E[m7 * COUT + lane];
    acc += ((a0 + a1) + (a2 + a3)) + ((a4 + a5) + (a6 + a7));
  }
  for (; i < cnt; ++i) acc += E[(int)lst[i] * COUT + lane];
  float dv = cnt > 0 ? rsqrtf((float)cnt) : 0.f;
  out[n * COUT + lane] = fmaxf(dv * acc, 0.f);
}

// ---------------------------------------------------------------------------
extern "C" void kernel_launch(void* const* d_in, const int* in_sizes, int n_in,
                              void* d_out, int out_size, void* d_ws, size_t ws_size,
                              hipStream_t stream) {
  const float* X = (const float*)d_in[0];   // (N_V, CIN)
  const float* H = (const float*)d_in[1];   // (N_V, M_E)
  const float* W = (const float*)d_in[2];   // (COUT, CIN)
  const float* b = (const float*)d_in[3];   // (COUT,)
  float* out = (float*)d_out;               // (N_V, COUT) fp32

  char* ws = (char*)d_ws;
  int* row_cnt = (int*)(ws + OFF_ROWCNT);
  int* col_cnt = (int*)(ws + OFF_COLCNT);
  unsigned short* row_list = (unsigned short*)(ws + OFF_ROWLIST);
  unsigned short* col_list = (unsigned short*)(ws + OFF_COLLIST);
  float* Yv = (float*)(ws + OFF_YV);
  float* E  = (float*)(ws + OFF_E);
  unsigned int* hist = (unsigned int*)(ws + OFF_HIST);

  // no memsets needed: row_cnt plain-stored, col_cnt written by k_scan,
  // hist fully written by k_hist before k_scan/k_fill read it.
  k_rows<<<N_V / 4, 256, 0, stream>>>((const uint4*)H, row_cnt, row_list);
  k_hist<<<CHUNKS, 256, 0, stream>>>(row_cnt, row_list, hist);
  k_scan<<<M_E / 256, 256, 0, stream>>>(hist, col_cnt);
  k_fill<<<CHUNKS, 256, 0, stream>>>(row_cnt, row_list, hist, col_list);
  k_project<<<N_V / 64, 256, 0, stream>>>(X, W, b, row_cnt, Yv);
  k_edge<<<M_E / 4, 256, 0, stream>>>(Yv, col_cnt, col_list, E);
  k_vertex<<<N_V / 4, 256, 0, stream>>>(E, row_cnt, row_list, out);
}

// Round 4
// 753.490 us; speedup vs baseline: 1.0008x; 1.0008x over previous
//
#include <hip/hip_runtime.h>
#include <hip/hip_bf16.h>
#include <stdint.h>

#define N_V   16384
#define M_E   8192
#define CIN   128
#define COUT  64
#define RCAP  128   // per-vertex edge-list capacity (Poisson(41): overflow ~1e-13)
#define CCAP  192   // per-edge vertex-list capacity (Poisson(82): overflow ~1e-18)
#define BCAP  16    // per-lane bucket slots (Binomial(128,.005): P(>16) ~ 1e-20)
#define CHUNKS 64   // row chunks for atomic-free column transpose
#define RPC   (N_V / CHUNKS)   // 256 rows per chunk

// workspace layout (bytes), all offsets 16B-aligned
#define OFF_ROWCNT  0
#define OFF_COLCNT  (N_V * 4)                         // 65536
#define OFF_ROWLIST (OFF_COLCNT + M_E * 4)            // 98304
#define OFF_COLLIST (OFF_ROWLIST + N_V * RCAP * 2)    // + 4 MB
#define OFF_YV      (OFF_COLLIST + M_E * CCAP * 2)    // + 3 MB
#define OFF_E       (OFF_YV + N_V * COUT * 4)         // + 4 MB
#define OFF_HIST    (OFF_E + M_E * COUT * 4)          // + 2 MB
// total: OFF_HIST + CHUNKS*M_E*4  ~= 15.2 MB

// ---------------------------------------------------------------------------
// K1: stream H once, one wave per row. Branchless inner loop: each lane
// pushes active columns into a private LDS bucket via the overwrite trick
// (write at slot min(cnt,BCAP), then cnt += active). No ballots, no exec-mask
// manipulation, no divergent branches -> loads pipeline to the HBM ceiling.
// Cross-lane coordination (shfl prefix sum) happens ONCE per row.
// ---------------------------------------------------------------------------
__global__ __launch_bounds__(256) void k_rows(
    const uint4* __restrict__ H4,
    int* __restrict__ row_cnt, unsigned short* __restrict__ row_list) {
  // [wave][slot][lane]: ds addr = slot*128 + lane*2 -> 2 lanes/bank (free)
  __shared__ unsigned short bucket[4][BCAP + 1][64];
  int wid  = threadIdx.x >> 6;
  int lane = threadIdx.x & 63;
  int n    = blockIdx.x * 4 + wid;                 // gridDim.x = N_V/4
  const uint4* rp = H4 + (size_t)n * (M_E / 4) + lane;
  unsigned short (*bk)[64] = bucket[wid];
  int cnt = 0;
  int mb  = lane * 4;                              // this lane's column base
#pragma unroll 8
  for (int it = 0; it < (M_E / 4) / 64; ++it) {    // 32 iterations
    uint4 v = rp[it * 64];
    // H entries are 0.0f / 1.0f: nonzero bits <=> nonzero float
    int w;
    w = cnt > BCAP ? BCAP : cnt; bk[w][lane] = (unsigned short)(mb + 0); cnt += (v.x != 0u);
    w = cnt > BCAP ? BCAP : cnt; bk[w][lane] = (unsigned short)(mb + 1); cnt += (v.y != 0u);
    w = cnt > BCAP ? BCAP : cnt; bk[w][lane] = (unsigned short)(mb + 2); cnt += (v.z != 0u);
    w = cnt > BCAP ? BCAP : cnt; bk[w][lane] = (unsigned short)(mb + 3); cnt += (v.w != 0u);
    mb += 256;
  }
  if (cnt > BCAP) cnt = BCAP;
  // inclusive prefix sum of per-lane counts across the wave (6 shfl steps)
  int pfx = cnt;
#pragma unroll
  for (int s = 1; s < 64; s <<= 1) {
    int t = __shfl_up(pfx, s, 64);
    if (lane >= s) pfx += t;
  }
  int total = __shfl(pfx, 63, 64);
  int start = pfx - cnt;
  unsigned short* rl = row_list + n * RCAP;
  for (int k = 0; k < cnt; ++k) {                  // max ~4 iterations
    int p = start + k;
    if (p < RCAP) rl[p] = bk[k][lane];
  }
  if (lane == 63) row_cnt[n] = total > RCAP ? RCAP : total;
}

// ---------------------------------------------------------------------------
// K1b-P1: per-chunk edge histogram via LDS atomics (no global atomics).
// One block per chunk of 256 rows.
// ---------------------------------------------------------------------------
__global__ __launch_bounds__(256) void k_hist(
    const int* __restrict__ row_cnt, const unsigned short* __restrict__ row_list,
    unsigned int* __restrict__ hist) {
  __shared__ unsigned int h[M_E];                  // 32 KB
  for (int i = threadIdx.x; i < M_E; i += 256) h[i] = 0u;
  __syncthreads();
  int n = blockIdx.x * RPC + threadIdx.x;          // gridDim.x = CHUNKS
  int cnt = row_cnt[n];
  const unsigned short* lst = row_list + n * RCAP;
  for (int i = 0; i < cnt; ++i) atomicAdd(&h[lst[i]], 1u);
  __syncthreads();
  unsigned int* out = hist + (size_t)blockIdx.x * M_E;
  for (int i = threadIdx.x; i < M_E; i += 256) out[i] = h[i];
}

// ---------------------------------------------------------------------------
// K1b-P2: exclusive scan over chunks per edge -> per-(chunk,edge) base
// offsets (in place) + total col_cnt. Coalesced, loads prefetchable.
// ---------------------------------------------------------------------------
__global__ __launch_bounds__(256) void k_scan(
    unsigned int* __restrict__ hist, int* __restrict__ col_cnt) {
  int e = blockIdx.x * 256 + threadIdx.x;          // gridDim.x = M_E/256
  unsigned int run = 0;
#pragma unroll 8
  for (int c = 0; c < CHUNKS; ++c) {
    unsigned int hv = hist[(size_t)c * M_E + e];
    hist[(size_t)c * M_E + e] = run;
    run += hv;
  }
  col_cnt[e] = (int)run;
}

// ---------------------------------------------------------------------------
// K1b-P3: re-walk row lists; LDS counters initialized to chunk bases, so
// atomicAdd return IS the global slot. Still zero global atomics.
// ---------------------------------------------------------------------------
__global__ __launch_bounds__(256) void k_fill(
    const int* __restrict__ row_cnt, const unsigned short* __restrict__ row_list,
    const unsigned int* __restrict__ hist, unsigned short* __restrict__ col_list) {
  __shared__ unsigned int h[M_E];                  // 32 KB
  const unsigned int* base = hist + (size_t)blockIdx.x * M_E;
  for (int i = threadIdx.x; i < M_E; i += 256) h[i] = base[i];
  __syncthreads();
  int n = blockIdx.x * RPC + threadIdx.x;
  int cnt = row_cnt[n];
  const unsigned short* lst = row_list + n * RCAP;
  for (int i = 0; i < cnt; ++i) {
    int e = lst[i];
    unsigned int slot = atomicAdd(&h[e], 1u);
    if (slot < CCAP) col_list[e * CCAP + slot] = (unsigned short)n;
  }
}

// ---------------------------------------------------------------------------
// K2: Yv[n,c] = dv[n] * (X[n,:] . W[c,:] + b[c])
// ---------------------------------------------------------------------------
__global__ __launch_bounds__(256) void k_project(
    const float* __restrict__ X, const float* __restrict__ W,
    const float* __restrict__ b, const int* __restrict__ row_cnt,
    float* __restrict__ Yv) {
  int wid  = threadIdx.x >> 6;
  int lane = threadIdx.x & 63;
  int cb   = __builtin_amdgcn_readfirstlane(wid);   // c-block 0..3, forced SGPR
  int n    = blockIdx.x * 64 + lane;                // gridDim.x = 256
  const float* xrow  = X + n * CIN;
  const float* wbase = W + cb * 16 * CIN;

  float acc[16];
#pragma unroll
  for (int j = 0; j < 16; ++j) acc[j] = 0.f;

  for (int k4 = 0; k4 < CIN / 4; ++k4) {
    float4 x = *(const float4*)(xrow + k4 * 4);
#pragma unroll
    for (int j = 0; j < 16; ++j) {
      float4 w = *(const float4*)(wbase + j * CIN + k4 * 4);
      acc[j] += x.x * w.x + x.y * w.y + x.z * w.z + x.w * w.w;
    }
  }

  int cnt  = row_cnt[n];
  float dv = cnt > 0 ? rsqrtf((float)cnt) : 0.f;
  float* yrow = Yv + n * COUT + cb * 16;
#pragma unroll
  for (int g = 0; g < 4; ++g) {
    float4 o;
    o.x = dv * (acc[4 * g + 0] + b[cb * 16 + 4 * g + 0]);
    o.y = dv * (acc[4 * g + 1] + b[cb * 16 + 4 * g + 1]);
    o.z = dv * (acc[4 * g + 2] + b[cb * 16 + 4 * g + 2]);
    o.w = dv * (acc[4 * g + 3] + b[cb * 16 + 4 * g + 3]);
    *(float4*)(yrow + 4 * g) = o;
  }
}

// ---------------------------------------------------------------------------
// K3: E[m,:] = (1/de_cnt[m]) * sum_{n in col_list[m]} Yv[n,:]
// One wave per hyperedge, lane = channel; 8 gathers in flight.
// ---------------------------------------------------------------------------
__global__ __launch_bounds__(256) void k_edge(
    const float* __restrict__ Yv, const int* __restrict__ col_cnt,
    const unsigned short* __restrict__ col_list, float* __restrict__ E) {
  int wid  = threadIdx.x >> 6;
  int lane = threadIdx.x & 63;
  int m    = blockIdx.x * 4 + wid;      // gridDim.x = M_E/4
  int realcnt = col_cnt[m];
  int cnt  = realcnt > CCAP ? CCAP : realcnt;
  const unsigned short* lst = col_list + m * CCAP;
  float acc = 0.f;
  int i = 0;
  for (; i + 8 <= cnt; i += 8) {
    uint4 u = *(const uint4*)(lst + i);
    int n0 = u.x & 0xffff, n1 = u.x >> 16;
    int n2 = u.y & 0xffff, n3 = u.y >> 16;
    int n4 = u.z & 0xffff, n5 = u.z >> 16;
    int n6 = u.w & 0xffff, n7 = u.w >> 16;
    float a0 = Yv[n0 * COUT + lane];
    float a1 = Yv[n1 * COUT + lane];
    float a2 = Yv[n2 * COUT + lane];
    float a3 = Yv[n3 * COUT + lane];
    float a4 = Yv[n4 * COUT + lane];
    float a5 = Yv[n5 * COUT + lane];
    float a6 = Yv[n6 * COUT + lane];
    float a7 = Yv[n7 * COUT + lane];
    acc += ((a0 + a1) + (a2 + a3)) + ((a4 + a5) + (a6 + a7));
  }
  for (; i < cnt; ++i) acc += Yv[(int)lst[i] * COUT + lane];
  float den = realcnt > 0 ? 1.f / (float)realcnt : 0.f;
  E[m * COUT + lane] = den * acc;
}

// ---------------------------------------------------------------------------
// K4: out[n,:] = relu(dv[n] * sum_{m in row_list[n]} E[m,:])
// ---------------------------------------------------------------------------
__global__ __launch_bounds__(256) void k_vertex(
    const float* __restrict__ E, const int* __restrict__ row_cnt,
    const unsigned short* __restrict__ row_list, float* __restrict__ out) {
  int wid  = threadIdx.x >> 6;
  int lane = threadIdx.x & 63;
  int n    = blockIdx.x * 4 + wid;      // gridDim.x = N_V/4
  int cnt  = row_cnt[n];
  const unsigned short* lst = row_list + n * RCAP;
  float acc = 0.f;
  int i = 0;
  for (; i + 8 <= cnt; i += 8) {
    uint4 u = *(const uint4*)(lst + i);
    int m0 = u.x & 0xffff, m1 = u.x >> 16;
    int m2 = u.y & 0xffff, m3 = u.y >> 16;
    int m4 = u.z & 0xffff, m5 = u.z >> 16;
    int m6 = u.w & 0xffff, m7 = u.w >> 16;
    float a0 = E[m0 * COUT + lane];
    float a1 = E[m1 * COUT + lane];
    float a2 = E[m2 * COUT + lane];
    float a3 = E[m3 * COUT + lane];
    float a4 = E[m4 * COUT + lane];
    float a5 = E[m5 * COUT + lane];
    float a6 = E[m6 * COUT + lane];
    float a7 = E[m7 * COUT + lane];
    acc += ((a0 + a1) + (a2 + a3)) + ((a4 + a5) + (a6 + a7));
  }
  for (; i < cnt; ++i) acc += E[(int)lst[i] * COUT + lane];
  float dv = cnt > 0 ? rsqrtf((float)cnt) : 0.f;
  out[n * COUT + lane] = fmaxf(dv * acc, 0.f);
}

// ---------------------------------------------------------------------------
extern "C" void kernel_launch(void* const* d_in, const int* in_sizes, int n_in,
                              void* d_out, int out_size, void* d_ws, size_t ws_size,
                              hipStream_t stream) {
  const float* X = (const float*)d_in[0];   // (N_V, CIN)
  const float* H = (const float*)d_in[1];   // (N_V, M_E)
  const float* W = (const float*)d_in[2];   // (COUT, CIN)
  const float* b = (const float*)d_in[3];   // (COUT,)
  float* out = (float*)d_out;               // (N_V, COUT) fp32

  char* ws = (char*)d_ws;
  int* row_cnt = (int*)(ws + OFF_ROWCNT);
  int* col_cnt = (int*)(ws + OFF_COLCNT);
  unsigned short* row_list = (unsigned short*)(ws + OFF_ROWLIST);
  unsigned short* col_list = (unsigned short*)(ws + OFF_COLLIST);
  float* Yv = (float*)(ws + OFF_YV);
  float* E  = (float*)(ws + OFF_E);
  unsigned int* hist = (unsigned int*)(ws + OFF_HIST);

  // no memsets needed: row_cnt plain-stored, col_cnt written by k_scan,
  // hist fully written by k_hist before k_scan/k_fill read it.
  k_rows<<<N_V / 4, 256, 0, stream>>>((const uint4*)H, row_cnt, row_list);
  k_hist<<<CHUNKS, 256, 0, stream>>>(row_cnt, row_list, hist);
  k_scan<<<M_E / 256, 256, 0, stream>>>(hist, col_cnt);
  k_fill<<<CHUNKS, 256, 0, stream>>>(row_cnt, row_list, hist, col_list);
  k_project<<<N_V / 64, 256, 0, stream>>>(X, W, b, row_cnt, Yv);
  k_edge<<<M_E / 4, 256, 0, stream>>>(Yv, col_cnt, col_list, E);
  k_vertex<<<N_V / 4, 256, 0, stream>>>(E, row_cnt, row_list, out);
}

// Round 5
// 734.574 us; speedup vs baseline: 1.0266x; 1.0258x over previous
//
#include <hip/hip_runtime.h>
#include <hip/hip_bf16.h>
#include <stdint.h>

#define N_V   16384
#define M_E   8192
#define CIN   128
#define COUT  64
#define RCAP  128   // per-vertex edge-list capacity (Poisson(41): overflow ~1e-13)
#define CCAP  192   // per-edge vertex-list capacity (Poisson(82): overflow ~1e-18)
#define BCAP  16    // per-lane bucket slots (Binomial(128,.005): P(>16) ~ 1e-20)

// workspace layout (bytes), all offsets 16B-aligned
#define OFF_ROWCNT  0
#define OFF_COLCNT  (N_V * 4)                         // 65536
#define OFF_ROWLIST (OFF_COLCNT + M_E * 4)            // 98304
#define OFF_COLLIST (OFF_ROWLIST + N_V * RCAP * 2)    // + 4 MB
#define OFF_YV      (OFF_COLLIST + M_E * CCAP * 2)    // + 3 MB
#define OFF_E       (OFF_YV + N_V * COUT * 4)         // + 4 MB
// total: OFF_E + M_E*COUT*4 ~= 13.1 MB

// ---------------------------------------------------------------------------
// K1: stream H once, one wave per row. Branchless inner loop (lane-private
// LDS buckets, overwrite trick) keeps the 512 MB stream at the HBM ceiling.
// Once per row: shfl prefix-sum -> row_list write, plus column-list scatter
// via INDEPENDENT global atomics (~1.3 per lane, unchained; latency hidden
// by the other streaming waves on the CU).
// ---------------------------------------------------------------------------
__global__ __launch_bounds__(256) void k_rows(
    const uint4* __restrict__ H4,
    int* __restrict__ row_cnt, unsigned short* __restrict__ row_list,
    int* __restrict__ col_cnt, unsigned short* __restrict__ col_list) {
  // [wave][slot][lane]: ds addr = slot*128 + lane*2 -> 2 lanes/bank (free)
  __shared__ unsigned short bucket[4][BCAP + 1][64];
  int wid  = threadIdx.x >> 6;
  int lane = threadIdx.x & 63;
  int n    = blockIdx.x * 4 + wid;                 // gridDim.x = N_V/4
  const uint4* rp = H4 + (size_t)n * (M_E / 4) + lane;
  unsigned short (*bk)[64] = bucket[wid];
  int cnt = 0;
  int mb  = lane * 4;                              // this lane's column base
#pragma unroll 8
  for (int it = 0; it < (M_E / 4) / 64; ++it) {    // 32 iterations
    uint4 v = rp[it * 64];
    // H entries are 0.0f / 1.0f: nonzero bits <=> nonzero float
    int w;
    w = cnt > BCAP ? BCAP : cnt; bk[w][lane] = (unsigned short)(mb + 0); cnt += (v.x != 0u);
    w = cnt > BCAP ? BCAP : cnt; bk[w][lane] = (unsigned short)(mb + 1); cnt += (v.y != 0u);
    w = cnt > BCAP ? BCAP : cnt; bk[w][lane] = (unsigned short)(mb + 2); cnt += (v.z != 0u);
    w = cnt > BCAP ? BCAP : cnt; bk[w][lane] = (unsigned short)(mb + 3); cnt += (v.w != 0u);
    mb += 256;
  }
  if (cnt > BCAP) cnt = BCAP;
  // inclusive prefix sum of per-lane counts across the wave (6 shfl steps)
  int pfx = cnt;
#pragma unroll
  for (int s = 1; s < 64; s <<= 1) {
    int t = __shfl_up(pfx, s, 64);
    if (lane >= s) pfx += t;
  }
  int total = __shfl(pfx, 63, 64);
  int start = pfx - cnt;
  unsigned short* rl = row_list + n * RCAP;
  for (int k = 0; k < cnt; ++k) {                  // max ~4 iterations
    int p = start + k;
    int e = bk[k][lane];
    if (p < RCAP) rl[p] = (unsigned short)e;
    int cp = atomicAdd(&col_cnt[e], 1);            // independent, unchained
    if (cp < CCAP) col_list[e * CCAP + cp] = (unsigned short)n;
  }
  if (lane == 63) row_cnt[n] = total > RCAP ? RCAP : total;
}

// ---------------------------------------------------------------------------
// K2: Yv[n,c] = dv[n] * (X[n,:] . W[c,:] + b[c])
// ---------------------------------------------------------------------------
__global__ __launch_bounds__(256) void k_project(
    const float* __restrict__ X, const float* __restrict__ W,
    const float* __restrict__ b, const int* __restrict__ row_cnt,
    float* __restrict__ Yv) {
  int wid  = threadIdx.x >> 6;
  int lane = threadIdx.x & 63;
  int cb   = __builtin_amdgcn_readfirstlane(wid);   // c-block 0..3, forced SGPR
  int n    = blockIdx.x * 64 + lane;                // gridDim.x = 256
  const float* xrow  = X + n * CIN;
  const float* wbase = W + cb * 16 * CIN;

  float acc[16];
#pragma unroll
  for (int j = 0; j < 16; ++j) acc[j] = 0.f;

  for (int k4 = 0; k4 < CIN / 4; ++k4) {
    float4 x = *(const float4*)(xrow + k4 * 4);
#pragma unroll
    for (int j = 0; j < 16; ++j) {
      float4 w = *(const float4*)(wbase + j * CIN + k4 * 4);
      acc[j] += x.x * w.x + x.y * w.y + x.z * w.z + x.w * w.w;
    }
  }

  int cnt  = row_cnt[n];
  float dv = cnt > 0 ? rsqrtf((float)cnt) : 0.f;
  float* yrow = Yv + n * COUT + cb * 16;
#pragma unroll
  for (int g = 0; g < 4; ++g) {
    float4 o;
    o.x = dv * (acc[4 * g + 0] + b[cb * 16 + 4 * g + 0]);
    o.y = dv * (acc[4 * g + 1] + b[cb * 16 + 4 * g + 1]);
    o.z = dv * (acc[4 * g + 2] + b[cb * 16 + 4 * g + 2]);
    o.w = dv * (acc[4 * g + 3] + b[cb * 16 + 4 * g + 3]);
    *(float4*)(yrow + 4 * g) = o;
  }
}

// ---------------------------------------------------------------------------
// K3: E[m,:] = (1/de_cnt[m]) * sum_{n in col_list[m]} Yv[n,:]
// One wave per hyperedge, lane = channel; 8 gathers in flight.
// ---------------------------------------------------------------------------
__global__ __launch_bounds__(256) void k_edge(
    const float* __restrict__ Yv, const int* __restrict__ col_cnt,
    const unsigned short* __restrict__ col_list, float* __restrict__ E) {
  int wid  = threadIdx.x >> 6;
  int lane = threadIdx.x & 63;
  int m    = blockIdx.x * 4 + wid;      // gridDim.x = M_E/4
  int realcnt = col_cnt[m];
  int cnt  = realcnt > CCAP ? CCAP : realcnt;
  const unsigned short* lst = col_list + m * CCAP;
  float acc = 0.f;
  int i = 0;
  for (; i + 8 <= cnt; i += 8) {
    uint4 u = *(const uint4*)(lst + i);
    int n0 = u.x & 0xffff, n1 = u.x >> 16;
    int n2 = u.y & 0xffff, n3 = u.y >> 16;
    int n4 = u.z & 0xffff, n5 = u.z >> 16;
    int n6 = u.w & 0xffff, n7 = u.w >> 16;
    float a0 = Yv[n0 * COUT + lane];
    float a1 = Yv[n1 * COUT + lane];
    float a2 = Yv[n2 * COUT + lane];
    float a3 = Yv[n3 * COUT + lane];
    float a4 = Yv[n4 * COUT + lane];
    float a5 = Yv[n5 * COUT + lane];
    float a6 = Yv[n6 * COUT + lane];
    float a7 = Yv[n7 * COUT + lane];
    acc += ((a0 + a1) + (a2 + a3)) + ((a4 + a5) + (a6 + a7));
  }
  for (; i < cnt; ++i) acc += Yv[(int)lst[i] * COUT + lane];
  float den = realcnt > 0 ? 1.f / (float)realcnt : 0.f;
  E[m * COUT + lane] = den * acc;
}

// ---------------------------------------------------------------------------
// K4: out[n,:] = relu(dv[n] * sum_{m in row_list[n]} E[m,:])
// ---------------------------------------------------------------------------
__global__ __launch_bounds__(256) void k_vertex(
    const float* __restrict__ E, const int* __restrict__ row_cnt,
    const unsigned short* __restrict__ row_list, float* __restrict__ out) {
  int wid  = threadIdx.x >> 6;
  int lane = threadIdx.x & 63;
  int n    = blockIdx.x * 4 + wid;      // gridDim.x = N_V/4
  int cnt  = row_cnt[n];
  const unsigned short* lst = row_list + n * RCAP;
  float acc = 0.f;
  int i = 0;
  for (; i + 8 <= cnt; i += 8) {
    uint4 u = *(const uint4*)(lst + i);
    int m0 = u.x & 0xffff, m1 = u.x >> 16;
    int m2 = u.y & 0xffff, m3 = u.y >> 16;
    int m4 = u.z & 0xffff, m5 = u.z >> 16;
    int m6 = u.w & 0xffff, m7 = u.w >> 16;
    float a0 = E[m0 * COUT + lane];
    float a1 = E[m1 * COUT + lane];
    float a2 = E[m2 * COUT + lane];
    float a3 = E[m3 * COUT + lane];
    float a4 = E[m4 * COUT + lane];
    float a5 = E[m5 * COUT + lane];
    float a6 = E[m6 * COUT + lane];
    float a7 = E[m7 * COUT + lane];
    acc += ((a0 + a1) + (a2 + a3)) + ((a4 + a5) + (a6 + a7));
  }
  for (; i < cnt; ++i) acc += E[(int)lst[i] * COUT + lane];
  float dv = cnt > 0 ? rsqrtf((float)cnt) : 0.f;
  out[n * COUT + lane] = fmaxf(dv * acc, 0.f);
}

// ---------------------------------------------------------------------------
extern "C" void kernel_launch(void* const* d_in, const int* in_sizes, int n_in,
                              void* d_out, int out_size, void* d_ws, size_t ws_size,
                              hipStream_t stream) {
  const float* X = (const float*)d_in[0];   // (N_V, CIN)
  const float* H = (const float*)d_in[1];   // (N_V, M_E)
  const float* W = (const float*)d_in[2];   // (COUT, CIN)
  const float* b = (const float*)d_in[3];   // (COUT,)
  float* out = (float*)d_out;               // (N_V, COUT) fp32

  char* ws = (char*)d_ws;
  int* row_cnt = (int*)(ws + OFF_ROWCNT);
  int* col_cnt = (int*)(ws + OFF_COLCNT);
  unsigned short* row_list = (unsigned short*)(ws + OFF_ROWLIST);
  unsigned short* col_list = (unsigned short*)(ws + OFF_COLLIST);
  float* Yv = (float*)(ws + OFF_YV);
  float* E  = (float*)(ws + OFF_E);

  // col_cnt must start at zero (ws poisoned to 0xAA each call); 32 KB, ~1 us
  hipMemsetAsync(col_cnt, 0, M_E * 4, stream);

  k_rows<<<N_V / 4, 256, 0, stream>>>((const uint4*)H, row_cnt, row_list,
                                      col_cnt, col_list);
  k_project<<<N_V / 64, 256, 0, stream>>>(X, W, b, row_cnt, Yv);
  k_edge<<<M_E / 4, 256, 0, stream>>>(Yv, col_cnt, col_list, E);
  k_vertex<<<N_V / 4, 256, 0, stream>>>(E, row_cnt, row_list, out);
}